// Round 2
// baseline (478.763 us; speedup 1.0000x reference)
//
#include <hip/hip_runtime.h>

// CSPN: affinity conv -> normalized 9-ch kernel -> 24 diffusion iterations.
// B=8, C_aff=8, H=W=512. All fp32.
constexpr int B = 8;
constexpr int H = 512;
constexpr int W = 512;
constexpr int N = B * H * W;           // 2,097,152 pixels
constexpr int HW = H * W;

// ---------------------------------------------------------------------------
// Kernel 1: affinity conv (1->8, 3x3 SAME, cross-correlation) + bias, then
// normalize into 9 SoA planes K[0..8][N].
//   aff[c] = b[c] + sum_{u,v} x[i+u-1, j+v-1] * Wa[c,0,u,v]
//   a = aff / sum|aff| ; s = sum a ; K0 = 1-s ; K[1..8] = a
// ---------------------------------------------------------------------------
__global__ __launch_bounds__(256) void cspn_gen_kernel(
    const float* __restrict__ x, const float* __restrict__ Wa,
    const float* __restrict__ ba, float* __restrict__ K) {
  int idx = blockIdx.x * 256 + threadIdx.x;
  if (idx >= N) return;
  int j = idx & (W - 1);
  int i = (idx >> 9) & (H - 1);
  const float* xb = x + (idx & ~(HW - 1));  // batch base (HW is pow2)

  // 3x3 neighborhood, zero-padded
  float v[9];
#pragma unroll
  for (int u = 0; u < 3; ++u) {
#pragma unroll
    for (int t = 0; t < 3; ++t) {
      int ii = i + u - 1, jj = j + t - 1;
      v[u * 3 + t] = (unsigned(ii) < (unsigned)H && unsigned(jj) < (unsigned)W)
                         ? xb[ii * W + jj]
                         : 0.0f;
    }
  }

  float aff[8];
  float abs_sum = 0.0f;
#pragma unroll
  for (int c = 0; c < 8; ++c) {
    float a = ba[c];
#pragma unroll
    for (int t = 0; t < 9; ++t) a += v[t] * Wa[c * 9 + t];
    aff[c] = a;
    abs_sum += fabsf(a);
  }
  float inv = 1.0f / abs_sum;
  float s = 0.0f;
#pragma unroll
  for (int c = 0; c < 8; ++c) {
    aff[c] *= inv;
    s += aff[c];
  }
  K[idx] = 1.0f - s;
#pragma unroll
  for (int c = 0; c < 8; ++c) K[(size_t)(c + 1) * N + idx] = aff[c];
}

// ---------------------------------------------------------------------------
// Kernel 2: one diffusion step.
//   xout[i,j] = K0*x[i,j] + K1*x[i,j-1] + K2*x[i,j+1]
//             + K3*x[i-1,j] + K4*x[i-1,j-1] + K5*x[i-1,j+1]
//             + K6*x[i+1,j] + K7*x[i+1,j-1] + K8*x[i+1,j+1]
// (cols[k] = x shifted by -off_k, OFFS = (0,0),(0,1),(0,-1),(1,0),(1,1),
//  (1,-1),(-1,0),(-1,1),(-1,-1); zero outside.)
// ---------------------------------------------------------------------------
__global__ __launch_bounds__(256) void cspn_diffuse(
    const float* __restrict__ xin, const float* __restrict__ K,
    float* __restrict__ xout) {
  int idx = blockIdx.x * 256 + threadIdx.x;
  if (idx >= N) return;
  int j = idx & (W - 1);
  int i = (idx >> 9) & (H - 1);
  const float* xb = xin + (idx & ~(HW - 1));

  auto g = [&](int ii, int jj) -> float {
    return (unsigned(ii) < (unsigned)H && unsigned(jj) < (unsigned)W)
               ? xb[ii * W + jj]
               : 0.0f;
  };

  float acc;
  acc  = K[idx]                * g(i, j);
  acc += K[(size_t)1 * N + idx] * g(i, j - 1);
  acc += K[(size_t)2 * N + idx] * g(i, j + 1);
  acc += K[(size_t)3 * N + idx] * g(i - 1, j);
  acc += K[(size_t)4 * N + idx] * g(i - 1, j - 1);
  acc += K[(size_t)5 * N + idx] * g(i - 1, j + 1);
  acc += K[(size_t)6 * N + idx] * g(i + 1, j);
  acc += K[(size_t)7 * N + idx] * g(i + 1, j - 1);
  acc += K[(size_t)8 * N + idx] * g(i + 1, j + 1);
  xout[idx] = acc;
}

extern "C" void kernel_launch(void* const* d_in, const int* in_sizes, int n_in,
                              void* d_out, int out_size, void* d_ws,
                              size_t ws_size, hipStream_t stream) {
  const float* x  = (const float*)d_in[0];   // [8,1,512,512]
  const float* Wa = (const float*)d_in[1];   // [8,1,3,3]
  const float* ba = (const float*)d_in[2];   // [8]
  float* out = (float*)d_out;                // [8,1,512,512]

  float* K  = (float*)d_ws;                  // 9*N floats = 75.5 MB
  float* xa = K + (size_t)9 * N;             // N floats   =  8.4 MB

  dim3 blk(256), grd(N / 256);
  cspn_gen_kernel<<<grd, blk, 0, stream>>>(x, Wa, ba, K);

  const float* src = x;
  for (int t = 0; t < 24; ++t) {
    float* dst = (t & 1) ? out : xa;  // t=23 (odd) -> final lands in d_out
    cspn_diffuse<<<grd, blk, 0, stream>>>(src, K, dst);
    src = dst;
  }
}

// Round 3
// 296.003 us; speedup vs baseline: 1.6174x; 1.6174x over previous
//
#include <hip/hip_runtime.h>

// CSPN: affinity conv -> normalized 9-ch kernel K (SoA planes) -> 24 diffusion
// iterations, fused T=4 steps per launch with K+x staged in LDS.
// B=8, H=W=512, fp32.
constexpr int B = 8;
constexpr int H = 512;
constexpr int W = 512;
constexpr int N = B * H * W;   // 2,097,152
constexpr int HW = H * W;

constexpr int TH = 16, TW = 64;       // output tile
constexpr int T = 4;                  // fused steps per launch
constexpr int KR = TH + 2 * (T - 1);  // 22  (K / step-0 region rows)
constexpr int KC = TW + 2 * (T - 1);  // 70
constexpr int XR = TH + 2 * T;        // 24  (x input region rows)
constexpr int XC = TW + 2 * T;        // 72
constexpr int NTH = H / TH;           // 32 tiles down
constexpr int NTW = W / TW;           // 8 tiles across
constexpr int NTILES = B * NTH * NTW; // 2048 (divisible by 8 -> bijective swz)
constexpr int NT = 512;               // threads per block

// ---------------------------------------------------------------------------
// Kernel 1: affinity conv (1->8, 3x3 SAME) + bias -> normalize -> 9 SoA planes
// ---------------------------------------------------------------------------
__global__ __launch_bounds__(256) void cspn_gen_kernel(
    const float* __restrict__ x, const float* __restrict__ Wa,
    const float* __restrict__ ba, float* __restrict__ K) {
  int idx = blockIdx.x * 256 + threadIdx.x;
  if (idx >= N) return;
  int j = idx & (W - 1);
  int i = (idx >> 9) & (H - 1);
  const float* xb = x + (idx & ~(HW - 1));

  float v[9];
#pragma unroll
  for (int u = 0; u < 3; ++u) {
#pragma unroll
    for (int t = 0; t < 3; ++t) {
      int ii = i + u - 1, jj = j + t - 1;
      v[u * 3 + t] = (unsigned(ii) < (unsigned)H && unsigned(jj) < (unsigned)W)
                         ? xb[ii * W + jj]
                         : 0.0f;
    }
  }

  float aff[8];
  float abs_sum = 0.0f;
#pragma unroll
  for (int c = 0; c < 8; ++c) {
    float a = ba[c];
#pragma unroll
    for (int t = 0; t < 9; ++t) a += v[t] * Wa[c * 9 + t];
    aff[c] = a;
    abs_sum += fabsf(a);
  }
  float inv = 1.0f / abs_sum;
  float s = 0.0f;
#pragma unroll
  for (int c = 0; c < 8; ++c) {
    aff[c] *= inv;
    s += aff[c];
  }
  K[idx] = 1.0f - s;
#pragma unroll
  for (int c = 0; c < 8; ++c) K[(size_t)(c + 1) * N + idx] = aff[c];
}

// ---------------------------------------------------------------------------
// Kernel 2: T fused diffusion steps on a 16x64 tile.
// Region at step s (tile-relative): rows [s-3, 19-s), cols [s-3, 67-s).
// K-region origin = tile + (-3,-3); X-region origin = tile + (-4,-4).
// Out-of-image pixels: K staged as 0 -> stencil result 0 (matches zero pad).
// ---------------------------------------------------------------------------
__global__ __launch_bounds__(NT, 4) void cspn_fused(
    const float* __restrict__ xin, const float* __restrict__ K,
    float* __restrict__ xout) {
  __shared__ float sK[9][KR][KC];   // 55.4 KB
  __shared__ float sX[2][XR][XC];   // 13.8 KB

  // bijective XCD-chunked swizzle (NTILES % 8 == 0)
  int bid = blockIdx.x;
  int wg = (bid & 7) * (NTILES / 8) + (bid >> 3);
  int b = wg / (NTH * NTW);
  int r = wg % (NTH * NTW);
  int ti0 = (r / NTW) * TH;
  int tj0 = (r % NTW) * TW;
  int tid = threadIdx.x;
  const float* xb = xin + (size_t)b * HW;

  // stage K (9 planes), zero outside image
  for (int p = tid; p < KR * KC; p += NT) {
    int li = p / KC, lj = p - li * KC;
    int gi = ti0 + li - (T - 1), gj = tj0 + lj - (T - 1);
    bool v = (unsigned)gi < (unsigned)H && (unsigned)gj < (unsigned)W;
    int gidx = b * HW + gi * W + gj;
#pragma unroll
    for (int c = 0; c < 9; ++c)
      sK[c][0][p] = v ? K[(size_t)c * N + gidx] : 0.0f;
  }
  // stage x region
  for (int p = tid; p < XR * XC; p += NT) {
    int li = p / XC, lj = p - li * XC;
    int gi = ti0 + li - T, gj = tj0 + lj - T;
    bool v = (unsigned)gi < (unsigned)H && (unsigned)gj < (unsigned)W;
    sX[0][0][p] = v ? xb[gi * W + gj] : 0.0f;
  }
  __syncthreads();

  int cur = 0;
#pragma unroll
  for (int s = 0; s < T - 1; ++s) {
    const int rows = KR - 2 * s, cols = KC - 2 * s;
    for (int p = tid; p < rows * cols; p += NT) {
      int li = p / cols + s, lj = p - (li - s) * cols + s;  // K-region coords
      int xi = li + 1, xj = lj + 1;                         // X-region coords
      float acc;
      acc  = sK[0][li][lj] * sX[cur][xi][xj];
      acc += sK[1][li][lj] * sX[cur][xi][xj - 1];
      acc += sK[2][li][lj] * sX[cur][xi][xj + 1];
      acc += sK[3][li][lj] * sX[cur][xi - 1][xj];
      acc += sK[4][li][lj] * sX[cur][xi - 1][xj - 1];
      acc += sK[5][li][lj] * sX[cur][xi - 1][xj + 1];
      acc += sK[6][li][lj] * sX[cur][xi + 1][xj];
      acc += sK[7][li][lj] * sX[cur][xi + 1][xj - 1];
      acc += sK[8][li][lj] * sX[cur][xi + 1][xj + 1];
      sX[cur ^ 1][xi][xj] = acc;
    }
    cur ^= 1;
    __syncthreads();
  }
  // final step: write tile directly to global (always fully in-image)
  {
    float* yb = xout + (size_t)b * HW;
    for (int p = tid; p < TH * TW; p += NT) {
      int oi = p / TW, oj = p - oi * TW;        // tile coords
      int li = oi + (T - 1), lj = oj + (T - 1); // K-region coords
      int xi = li + 1, xj = lj + 1;
      float acc;
      acc  = sK[0][li][lj] * sX[cur][xi][xj];
      acc += sK[1][li][lj] * sX[cur][xi][xj - 1];
      acc += sK[2][li][lj] * sX[cur][xi][xj + 1];
      acc += sK[3][li][lj] * sX[cur][xi - 1][xj];
      acc += sK[4][li][lj] * sX[cur][xi - 1][xj - 1];
      acc += sK[5][li][lj] * sX[cur][xi - 1][xj + 1];
      acc += sK[6][li][lj] * sX[cur][xi + 1][xj];
      acc += sK[7][li][lj] * sX[cur][xi + 1][xj - 1];
      acc += sK[8][li][lj] * sX[cur][xi + 1][xj + 1];
      yb[(ti0 + oi) * W + (tj0 + oj)] = acc;
    }
  }
}

extern "C" void kernel_launch(void* const* d_in, const int* in_sizes, int n_in,
                              void* d_out, int out_size, void* d_ws,
                              size_t ws_size, hipStream_t stream) {
  const float* x  = (const float*)d_in[0];
  const float* Wa = (const float*)d_in[1];
  const float* ba = (const float*)d_in[2];
  float* out = (float*)d_out;

  float* K  = (float*)d_ws;             // 9*N floats = 75.5 MB
  float* xa = K + (size_t)9 * N;        // N floats
  cspn_gen_kernel<<<dim3(N / 256), dim3(256), 0, stream>>>(x, Wa, ba, K);

  const float* src = x;
  for (int l = 0; l < 24 / T; ++l) {    // 6 launches of 4 fused steps
    float* dst = (l & 1) ? out : xa;    // l=5 (odd) -> final lands in d_out
    cspn_fused<<<dim3(NTILES), dim3(NT), 0, stream>>>(src, K, dst);
    src = dst;
  }
}

// Round 6
// 163.770 us; speedup vs baseline: 2.9234x; 1.8074x over previous
//
#include <hip/hip_runtime.h>

// CSPN: affinity conv -> normalized 9-ch kernel K (SoA planes) -> 24 diffusion
// steps, fused T=6 per launch. K lives in REGISTERS (step-invariant),
// X double-buffered in LDS with float4 stencil reads.
constexpr int B = 8, H = 512, W = 512;
constexpr int N = B * H * W;       // 2,097,152
constexpr int HW = H * W;

constexpr int TT = 32;             // output tile side
constexpr int T  = 6;              // fused steps per launch (24 = 4*6)
constexpr int XR = TT + 2 * T;     // 44: staged X region side
constexpr int XE = XR * XR;        // 1936 floats per buffer
constexpr int NG = XR / 4;         // 11 col-groups per row
constexpr int CR = XR - 2;         // 42 computed rows (xi = 1..42)
constexpr int NGT = CR * NG;       // 462 groups (1 per thread)
constexpr int NTH = H / TT, NTW = W / TT;   // 16 x 16
constexpr int NTILES = B * NTH * NTW;       // 2048 (div by 8 -> bijective swz)
constexpr int NT = 512;

// ---------------------------------------------------------------------------
// Kernel 1: affinity conv (1->8, 3x3 SAME) + bias -> normalize -> 9 SoA planes
// ---------------------------------------------------------------------------
__global__ __launch_bounds__(256) void cspn_gen_kernel(
    const float* __restrict__ x, const float* __restrict__ Wa,
    const float* __restrict__ ba, float* __restrict__ K) {
  int idx = blockIdx.x * 256 + threadIdx.x;
  if (idx >= N) return;
  int j = idx & (W - 1);
  int i = (idx >> 9) & (H - 1);
  const float* xb = x + (idx & ~(HW - 1));

  float v[9];
#pragma unroll
  for (int u = 0; u < 3; ++u) {
#pragma unroll
    for (int t = 0; t < 3; ++t) {
      int ii = i + u - 1, jj = j + t - 1;
      v[u * 3 + t] = (unsigned(ii) < (unsigned)H && unsigned(jj) < (unsigned)W)
                         ? xb[ii * W + jj]
                         : 0.0f;
    }
  }

  float aff[8];
  float abs_sum = 0.0f;
#pragma unroll
  for (int c = 0; c < 8; ++c) {
    float a = ba[c];
#pragma unroll
    for (int t = 0; t < 9; ++t) a += v[t] * Wa[c * 9 + t];
    aff[c] = a;
    abs_sum += fabsf(a);
  }
  float inv = 1.0f / abs_sum;
  float s = 0.0f;
#pragma unroll
  for (int c = 0; c < 8; ++c) {
    aff[c] *= inv;
    s += aff[c];
  }
  K[idx] = 1.0f - s;
#pragma unroll
  for (int c = 0; c < 8; ++c) K[(size_t)(c + 1) * N + idx] = aff[c];
}

// ---------------------------------------------------------------------------
// Kernel 2: T=6 fused diffusion steps, 32x32 tile.
// X region 44x44 (origin tile-(6,6)), double-buffered. Each thread owns the
// 4-px group (xi, xj0..xj0+3) for all steps; its 9 K values/px in registers.
// Compute rows 1..42, all 44 cols every step; validity shrinks 1/side/step;
// valid(6) = [6..37]^2 = exactly the tile. Col 0/43 and rows touching the
// never-rewritten border rows go stale/NaN but stay outside the valid core.
// ---------------------------------------------------------------------------
__global__ __launch_bounds__(NT) void cspn_fused(
    const float* __restrict__ xin, const float* __restrict__ Kg,
    float* __restrict__ xout) {
  __shared__ __align__(16) float sBuf[64 + 2 * XE + 64];  // front/back guards
  float* sX = sBuf + 64;

  int bid = blockIdx.x;
  int wg = (bid & 7) * (NTILES / 8) + (bid >> 3);  // XCD-chunked swizzle
  int b  = wg / (NTH * NTW);
  int rr = wg % (NTH * NTW);
  int ti0 = (rr / NTW) * TT, tj0 = (rr % NTW) * TT;
  int tid = threadIdx.x;

  bool active = tid < NGT;
  int xi  = 1 + tid / NG;          // 1..42
  int xj0 = (tid % NG) * 4;        // 0,4,...,40

  // ---- one-time K fragment load: 9 planes x float4 (as 2x float2; the
  //      global offset is ≡8 mod 16 so b128 would be misaligned) ----
  float4 kk[9];
  {
    int gi  = ti0 + xi - T;
    int gj0 = tj0 + xj0 - T;       // even
    bool rowv = active && (unsigned)gi < (unsigned)H;
    const float* Kb = Kg + (size_t)b * HW + (size_t)(rowv ? gi : 0) * W;
#pragma unroll
    for (int c = 0; c < 9; ++c) {
      const float* Kp = Kb + (size_t)c * N;
      float2 lo = (rowv && (unsigned)gj0 < (unsigned)W)
                      ? *reinterpret_cast<const float2*>(Kp + gj0)
                      : make_float2(0.f, 0.f);
      float2 hi = (rowv && (unsigned)(gj0 + 2) < (unsigned)W)
                      ? *reinterpret_cast<const float2*>(Kp + gj0 + 2)
                      : make_float2(0.f, 0.f);
      kk[c] = make_float4(lo.x, lo.y, hi.x, hi.y);
    }
  }

  // ---- stage X region (zero outside image) into buffer 0 ----
  const float* xb = xin + (size_t)b * HW;
  for (int p = tid; p < XE; p += NT) {
    int li = p / XR, lj = p - li * XR;
    int gi = ti0 + li - T, gj = tj0 + lj - T;
    bool v = (unsigned)gi < (unsigned)H && (unsigned)gj < (unsigned)W;
    sX[p] = v ? xb[gi * W + gj] : 0.f;
  }
  __syncthreads();

  // ---- T fused steps ----
  int base = xi * XR + xj0;
#pragma unroll
  for (int s = 0; s < T; ++s) {
    const float* Xc = sX + (s & 1) * XE;
    float* Xn = sX + (((s & 1) ^ 1)) * XE;
    if (active) {
      const float* rm = Xc + base - XR;
      const float* rc = Xc + base;
      const float* rp = Xc + base + XR;
      float4 c0 = *reinterpret_cast<const float4*>(rm);
      float  l0 = rm[-1], r0 = rm[4];
      float4 c1 = *reinterpret_cast<const float4*>(rc);
      float  l1 = rc[-1], r1 = rc[4];
      float4 c2 = *reinterpret_cast<const float4*>(rp);
      float  l2 = rp[-1], r2 = rp[4];
      float4 acc;
      acc.x = kk[0].x * c1.x + kk[1].x * l1   + kk[2].x * c1.y
            + kk[3].x * c0.x + kk[4].x * l0   + kk[5].x * c0.y
            + kk[6].x * c2.x + kk[7].x * l2   + kk[8].x * c2.y;
      acc.y = kk[0].y * c1.y + kk[1].y * c1.x + kk[2].y * c1.z
            + kk[3].y * c0.y + kk[4].y * c0.x + kk[5].y * c0.z
            + kk[6].y * c2.y + kk[7].y * c2.x + kk[8].y * c2.z;
      acc.z = kk[0].z * c1.z + kk[1].z * c1.y + kk[2].z * c1.w
            + kk[3].z * c0.z + kk[4].z * c0.y + kk[5].z * c0.w
            + kk[6].z * c2.z + kk[7].z * c2.y + kk[8].z * c2.w;
      acc.w = kk[0].w * c1.w + kk[1].w * c1.z + kk[2].w * r1
            + kk[3].w * c0.w + kk[4].w * c0.z + kk[5].w * r0
            + kk[6].w * c2.w + kk[7].w * c2.z + kk[8].w * r2;
      *reinterpret_cast<float4*>(Xn + base) = acc;
    }
    __syncthreads();
  }

  // ---- write 32x32 tile (step-6 result is in buffer 0; T even) ----
  float* yb = xout + (size_t)b * HW;
  int i  = tid >> 4;               // 0..31
  int pj = (tid & 15) * 2;         // 0..30
  float2 v = *reinterpret_cast<const float2*>(sX + (i + T) * XR + (pj + T));
  *reinterpret_cast<float2*>(yb + (size_t)(ti0 + i) * W + (tj0 + pj)) = v;
}

extern "C" void kernel_launch(void* const* d_in, const int* in_sizes, int n_in,
                              void* d_out, int out_size, void* d_ws,
                              size_t ws_size, hipStream_t stream) {
  const float* x  = (const float*)d_in[0];
  const float* Wa = (const float*)d_in[1];
  const float* ba = (const float*)d_in[2];
  float* out = (float*)d_out;

  float* K  = (float*)d_ws;            // 9*N floats = 75.5 MB
  float* xa = K + (size_t)9 * N;       // N floats
  cspn_gen_kernel<<<dim3(N / 256), dim3(256), 0, stream>>>(x, Wa, ba, K);

  const float* src = x;
  for (int l = 0; l < 24 / T; ++l) {   // 4 launches of 6 fused steps
    float* dst = (l & 1) ? out : xa;   // l=3 (odd) -> final lands in d_out
    cspn_fused<<<dim3(NTILES), dim3(NT), 0, stream>>>(src, K, dst);
    src = dst;
  }
}

// Round 10
// 155.703 us; speedup vs baseline: 3.0748x; 1.0518x over previous
//
#include <hip/hip_runtime.h>
#include <hip/hip_fp16.h>

// CSPN: affinity conv -> 8 normalized a-planes packed fp16 AoS (16 B/px) ->
// 24 diffusion steps fused T=6/launch. K in registers (K0 recomputed),
// X double-buffered in LDS with float4 stencil reads.
constexpr int B = 8, H = 512, W = 512;
constexpr int N = B * H * W;       // 2,097,152
constexpr int HW = H * W;

constexpr int TT = 32;             // output tile side
constexpr int T  = 6;              // fused steps per launch (24 = 4*6)
constexpr int XR = TT + 2 * T;     // 44: staged X region side
constexpr int XE = XR * XR;        // 1936 floats per buffer
constexpr int NG = XR / 4;         // 11 col-groups per row
constexpr int CR = XR - 2;         // 42 computed rows (xi = 1..42)
constexpr int NGT = CR * NG;       // 462 groups (1 per thread)
constexpr int NTH = H / TT, NTW = W / TT;   // 16 x 16
constexpr int NTILES = B * NTH * NTW;       // 2048 (div by 8 -> bijective swz)
constexpr int NT = 512;

// ---------------------------------------------------------------------------
// Kernel 1: affinity conv (1->8, 3x3 SAME) + bias -> normalize -> fp16 AoS.
// Kh[px][0..7] = a[c] (half). K0 is NOT stored (recomputed as 1 - sum a).
// ---------------------------------------------------------------------------
__global__ __launch_bounds__(256) void cspn_gen_kernel(
    const float* __restrict__ x, const float* __restrict__ Wa,
    const float* __restrict__ ba, __half* __restrict__ Kh) {
  int idx = blockIdx.x * 256 + threadIdx.x;
  if (idx >= N) return;
  int j = idx & (W - 1);
  int i = (idx >> 9) & (H - 1);
  const float* xb = x + (idx & ~(HW - 1));

  float v[9];
#pragma unroll
  for (int u = 0; u < 3; ++u) {
#pragma unroll
    for (int t = 0; t < 3; ++t) {
      int ii = i + u - 1, jj = j + t - 1;
      v[u * 3 + t] = (unsigned(ii) < (unsigned)H && unsigned(jj) < (unsigned)W)
                         ? xb[ii * W + jj]
                         : 0.0f;
    }
  }

  float aff[8];
  float abs_sum = 0.0f;
#pragma unroll
  for (int c = 0; c < 8; ++c) {
    float a = ba[c];
#pragma unroll
    for (int t = 0; t < 9; ++t) a += v[t] * Wa[c * 9 + t];
    aff[c] = a;
    abs_sum += fabsf(a);
  }
  float inv = 1.0f / abs_sum;
#pragma unroll
  for (int c = 0; c < 8; ++c) aff[c] *= inv;

  union { uint4 u; __half2 h[4]; } pk;
#pragma unroll
  for (int c = 0; c < 4; ++c)
    pk.h[c] = __floats2half2_rn(aff[2 * c], aff[2 * c + 1]);
  *reinterpret_cast<uint4*>(Kh + (size_t)idx * 8) = pk.u;
}

// ---------------------------------------------------------------------------
// Kernel 2: T=6 fused diffusion steps, 32x32 tile. X region 44x44
// (origin tile-(6,6)), double-buffered. Thread owns 4-px group (xi,xj0..+3)
// for all steps; K fragment = 4 contiguous half8 (64 B) unpacked to 36 VGPRs.
// Out-of-image px: a=0 -> K0=1 -> copies its staged 0 forever (zero-pad ok).
// Valid core shrinks 1/side/step; valid(6) = exactly the 32x32 tile.
// ---------------------------------------------------------------------------
__global__ __launch_bounds__(NT) void cspn_fused(
    const float* __restrict__ xin, const __half* __restrict__ Kh,
    float* __restrict__ xout) {
  __shared__ __align__(16) float sBuf[64 + 2 * XE + 64];  // front/back guards
  float* sX = sBuf + 64;

  int bid = blockIdx.x;
  int wg = (bid & 7) * (NTILES / 8) + (bid >> 3);  // XCD-chunked swizzle
  int b  = wg / (NTH * NTW);
  int rr = wg % (NTH * NTW);
  int ti0 = (rr / NTW) * TT, tj0 = (rr % NTW) * TT;
  int tid = threadIdx.x;

  bool active = tid < NGT;
  int xi  = 1 + tid / NG;          // 1..42
  int xj0 = (tid % NG) * 4;        // 0,4,...,40

  // ---- one-time K fragment: 4 px x half8 (16 B each, 16-B aligned) ----
  float kkv[9][4];                 // [tap][px], fully static indexing
  {
    int gi  = ti0 + xi - T;
    int gj0 = tj0 + xj0 - T;
    bool rowv = active && (unsigned)gi < (unsigned)H;
    const __half* Kb =
        Kh + ((size_t)b * HW + (size_t)(rowv ? gi : 0) * W) * 8;
#pragma unroll
    for (int p = 0; p < 4; ++p) {
      int gj = gj0 + p;
      union { uint4 u; __half2 h[4]; } pk;
      pk.u = make_uint4(0u, 0u, 0u, 0u);
      if (rowv && (unsigned)gj < (unsigned)W)
        pk.u = *reinterpret_cast<const uint4*>(Kb + (size_t)gj * 8);
      float2 f01 = __half22float2(pk.h[0]);
      float2 f23 = __half22float2(pk.h[1]);
      float2 f45 = __half22float2(pk.h[2]);
      float2 f67 = __half22float2(pk.h[3]);
      float s = f01.x + f01.y + f23.x + f23.y + f45.x + f45.y + f67.x + f67.y;
      kkv[0][p] = 1.0f - s;
      kkv[1][p] = f01.x;  kkv[2][p] = f01.y;
      kkv[3][p] = f23.x;  kkv[4][p] = f23.y;
      kkv[5][p] = f45.x;  kkv[6][p] = f45.y;
      kkv[7][p] = f67.x;  kkv[8][p] = f67.y;
    }
  }

  // ---- stage X region (zero outside image) into buffer 0 ----
  const float* xb = xin + (size_t)b * HW;
  for (int p = tid; p < XE; p += NT) {
    int li = p / XR, lj = p - li * XR;
    int gi = ti0 + li - T, gj = tj0 + lj - T;
    bool v = (unsigned)gi < (unsigned)H && (unsigned)gj < (unsigned)W;
    sX[p] = v ? xb[gi * W + gj] : 0.f;
  }
  __syncthreads();

  // ---- T fused steps ----
  int base = xi * XR + xj0;
#pragma unroll
  for (int s = 0; s < T; ++s) {
    const float* Xc = sX + (s & 1) * XE;
    float* Xn = sX + (((s & 1) ^ 1)) * XE;
    if (active) {
      const float* rm = Xc + base - XR;
      const float* rc = Xc + base;
      const float* rp = Xc + base + XR;
      float4 c0 = *reinterpret_cast<const float4*>(rm);
      float  l0 = rm[-1], r0 = rm[4];
      float4 c1 = *reinterpret_cast<const float4*>(rc);
      float  l1 = rc[-1], r1 = rc[4];
      float4 c2 = *reinterpret_cast<const float4*>(rp);
      float  l2 = rp[-1], r2 = rp[4];
      float4 acc;
      acc.x = kkv[0][0] * c1.x + kkv[1][0] * l1   + kkv[2][0] * c1.y
            + kkv[3][0] * c0.x + kkv[4][0] * l0   + kkv[5][0] * c0.y
            + kkv[6][0] * c2.x + kkv[7][0] * l2   + kkv[8][0] * c2.y;
      acc.y = kkv[0][1] * c1.y + kkv[1][1] * c1.x + kkv[2][1] * c1.z
            + kkv[3][1] * c0.y + kkv[4][1] * c0.x + kkv[5][1] * c0.z
            + kkv[6][1] * c2.y + kkv[7][1] * c2.x + kkv[8][1] * c2.z;
      acc.z = kkv[0][2] * c1.z + kkv[1][2] * c1.y + kkv[2][2] * c1.w
            + kkv[3][2] * c0.z + kkv[4][2] * c0.y + kkv[5][2] * c0.w
            + kkv[6][2] * c2.z + kkv[7][2] * c2.y + kkv[8][2] * c2.w;
      acc.w = kkv[0][3] * c1.w + kkv[1][3] * c1.z + kkv[2][3] * r1
            + kkv[3][3] * c0.w + kkv[4][3] * c0.z + kkv[5][3] * r0
            + kkv[6][3] * c2.w + kkv[7][3] * c2.z + kkv[8][3] * r2;
      *reinterpret_cast<float4*>(Xn + base) = acc;
    }
    __syncthreads();
  }

  // ---- write 32x32 tile (step-6 result is in buffer 0; T even) ----
  float* yb = xout + (size_t)b * HW;
  int i  = tid >> 4;               // 0..31
  int pj = (tid & 15) * 2;         // 0..30
  float2 v = *reinterpret_cast<const float2*>(sX + (i + T) * XR + (pj + T));
  *reinterpret_cast<float2*>(yb + (size_t)(ti0 + i) * W + (tj0 + pj)) = v;
}

extern "C" void kernel_launch(void* const* d_in, const int* in_sizes, int n_in,
                              void* d_out, int out_size, void* d_ws,
                              size_t ws_size, hipStream_t stream) {
  const float* x  = (const float*)d_in[0];
  const float* Wa = (const float*)d_in[1];
  const float* ba = (const float*)d_in[2];
  float* out = (float*)d_out;

  __half* Kh = (__half*)d_ws;                   // 8N halves = 33.5 MB
  float* xa = (float*)d_ws + 4 * (size_t)N;     // after 16N bytes
  cspn_gen_kernel<<<dim3(N / 256), dim3(256), 0, stream>>>(x, Wa, ba, Kh);

  const float* src = x;
  for (int l = 0; l < 24 / T; ++l) {   // 4 launches of 6 fused steps
    float* dst = (l & 1) ? out : xa;   // l=3 (odd) -> final lands in d_out
    cspn_fused<<<dim3(NTILES), dim3(NT), 0, stream>>>(src, Kh, dst);
    src = dst;
  }
}

// Round 11
// 119.311 us; speedup vs baseline: 4.0127x; 1.3050x over previous
//
#include <hip/hip_runtime.h>
#include <hip/hip_fp16.h>

// CSPN: affinity conv -> 8 normalized a-planes fp16 AoS (16 B/px) -> 24
// diffusion steps fused T=6/launch. K packed fp16 in regs (K0 recomputed,
// fp32), own 4-px row carried in registers across steps, X dbuf in LDS.
constexpr int B = 8, H = 512, W = 512;
constexpr int N = B * H * W;       // 2,097,152
constexpr int HW = H * W;

constexpr int TT = 32;             // output tile side
constexpr int T  = 6;              // fused steps per launch (24 = 4*6)
constexpr int XR = TT + 2 * T;     // 44: staged X region side
constexpr int XE = XR * XR;        // 1936 floats per buffer
constexpr int NG = XR / 4;         // 11 col-groups per row
constexpr int CR = XR - 2;         // 42 computed rows (xi = 1..42)
constexpr int NGT = CR * NG;       // 462 active threads
constexpr int NTH = H / TT, NTW = W / TT;   // 16 x 16
constexpr int NTILES = B * NTH * NTW;       // 2048 (div by 8 -> bijective swz)
constexpr int NT = 512;

// ---------------------------------------------------------------------------
// Kernel 1: affinity conv (1->8, 3x3 SAME) + bias -> normalize -> fp16 AoS.
// Kh[px][0..7] = a[c]. K0 not stored (recomputed as 1 - sum a).
// ---------------------------------------------------------------------------
__global__ __launch_bounds__(256) void cspn_gen_kernel(
    const float* __restrict__ x, const float* __restrict__ Wa,
    const float* __restrict__ ba, __half* __restrict__ Kh) {
  int idx = blockIdx.x * 256 + threadIdx.x;
  if (idx >= N) return;
  int j = idx & (W - 1);
  int i = (idx >> 9) & (H - 1);
  const float* xb = x + (idx & ~(HW - 1));

  float v[9];
#pragma unroll
  for (int u = 0; u < 3; ++u) {
#pragma unroll
    for (int t = 0; t < 3; ++t) {
      int ii = i + u - 1, jj = j + t - 1;
      v[u * 3 + t] = (unsigned(ii) < (unsigned)H && unsigned(jj) < (unsigned)W)
                         ? xb[ii * W + jj]
                         : 0.0f;
    }
  }

  float aff[8];
  float abs_sum = 0.0f;
#pragma unroll
  for (int c = 0; c < 8; ++c) {
    float a = ba[c];
#pragma unroll
    for (int t = 0; t < 9; ++t) a += v[t] * Wa[c * 9 + t];
    aff[c] = a;
    abs_sum += fabsf(a);
  }
  float inv = 1.0f / abs_sum;
#pragma unroll
  for (int c = 0; c < 8; ++c) aff[c] *= inv;

  union { uint4 u; __half2 h[4]; } pk;
#pragma unroll
  for (int c = 0; c < 4; ++c)
    pk.h[c] = __floats2half2_rn(aff[2 * c], aff[2 * c + 1]);
  *reinterpret_cast<uint4*>(Kh + (size_t)idx * 8) = pk.u;
}

// ---------------------------------------------------------------------------
// Kernel 2: T=6 fused steps, 32x32 tile, X region 44x44 double-buffered.
// Thread owns 4-px group (xi, xj0..+3): K packed fp16 in 16 half2 + 4 fp32
// K0; its own 4 px ride in registers (c1) between steps — only neighbor rows
// and row-edge scalars come from LDS. launch_bounds(512,6) targets <=85 VGPR
// for 3 resident blocks/CU.
// ---------------------------------------------------------------------------
#define H2F(h) __half2float(h)

__global__ __launch_bounds__(NT, 6) void cspn_fused(
    const float* __restrict__ xin, const __half* __restrict__ Kh,
    float* __restrict__ xout) {
  __shared__ __align__(16) float sBuf[64 + 2 * XE + 64];  // front/back guards
  float* sX = sBuf + 64;

  int bid = blockIdx.x;
  int wg = (bid & 7) * (NTILES / 8) + (bid >> 3);  // XCD-chunked swizzle
  int b  = wg / (NTH * NTW);
  int rr = wg % (NTH * NTW);
  int ti0 = (rr / NTW) * TT, tj0 = (rr % NTW) * TT;
  int tid = threadIdx.x;

  bool active = tid < NGT;
  int xi  = 1 + tid / NG;          // 1..42
  int xj0 = (tid % NG) * 4;        // 0,4,...,40

  // ---- one-time K fragment: 4 px x half8, kept PACKED (16 half2 regs) ----
  __half2 kh[4][4];                // [px][tap-pair]: (a1,a2)(a3,a4)(a5,a6)(a7,a8)
  float4 k0;                       // fp32 center tap per px
  {
    int gi  = ti0 + xi - T;
    int gj0 = tj0 + xj0 - T;
    bool rowv = active && (unsigned)gi < (unsigned)H;
    const __half* Kb =
        Kh + ((size_t)b * HW + (size_t)(rowv ? gi : 0) * W) * 8;
    float k0v[4];
#pragma unroll
    for (int p = 0; p < 4; ++p) {
      int gj = gj0 + p;
      union { uint4 u; __half2 h[4]; } pk;
      pk.u = make_uint4(0u, 0u, 0u, 0u);
      if (rowv && (unsigned)gj < (unsigned)W)
        pk.u = *reinterpret_cast<const uint4*>(Kb + (size_t)gj * 8);
      float2 f01 = __half22float2(pk.h[0]);
      float2 f23 = __half22float2(pk.h[1]);
      float2 f45 = __half22float2(pk.h[2]);
      float2 f67 = __half22float2(pk.h[3]);
      k0v[p] = 1.0f - (f01.x + f01.y + f23.x + f23.y +
                       f45.x + f45.y + f67.x + f67.y);
      kh[p][0] = pk.h[0]; kh[p][1] = pk.h[1];
      kh[p][2] = pk.h[2]; kh[p][3] = pk.h[3];
    }
    k0 = make_float4(k0v[0], k0v[1], k0v[2], k0v[3]);
  }

  // ---- zero LDS guards + buf1 border rows (never computed) ----
  if (tid < 64) {
    sBuf[tid] = 0.f;
    sBuf[64 + 2 * XE + tid] = 0.f;
  }
  if (tid < 2 * XR) {              // buf1 rows 0 and 43
    int r = (tid < XR) ? 0 : (XR - 1);
    int c = (tid < XR) ? tid : tid - XR;
    sX[XE + r * XR + c] = 0.f;
  }

  // ---- stage X region into buf0 (float2-vectorized; W even -> no split) ----
  const float* xb = xin + (size_t)b * HW;
  for (int p = tid; p < XR * (XR / 2); p += NT) {   // 968 float2
    int li = p / (XR / 2), g = p - li * (XR / 2);
    int gi = ti0 + li - T, gj = tj0 + 2 * g - T;
    float2 v = make_float2(0.f, 0.f);
    if ((unsigned)gi < (unsigned)H && (unsigned)gj < (unsigned)W)
      v = *reinterpret_cast<const float2*>(xb + gi * W + gj);
    *reinterpret_cast<float2*>(sX + li * XR + 2 * g) = v;
  }
  __syncthreads();

  // ---- T fused steps; own 4 px live in c1 ----
  int base = xi * XR + xj0;
  float4 c1;
  if (active) c1 = *reinterpret_cast<const float4*>(sX + base);
#pragma unroll
  for (int s = 0; s < T; ++s) {
    const float* Xc = sX + (s & 1) * XE;
    float* Xn = sX + (((s & 1) ^ 1)) * XE;
    if (active) {
      const float* rm = Xc + base - XR;
      const float* rp = Xc + base + XR;
      float4 c0 = *reinterpret_cast<const float4*>(rm);
      float  l0 = rm[-1], r0 = rm[4];
      float4 c2 = *reinterpret_cast<const float4*>(rp);
      float  l2 = rp[-1], r2 = rp[4];
      float  l1 = Xc[base - 1], r1 = Xc[base + 4];
      float4 acc;
      acc.x = k0.x * c1.x
            + H2F(kh[0][0].x) * l1   + H2F(kh[0][0].y) * c1.y
            + H2F(kh[0][1].x) * c0.x + H2F(kh[0][1].y) * l0
            + H2F(kh[0][2].x) * c0.y + H2F(kh[0][2].y) * c2.x
            + H2F(kh[0][3].x) * l2   + H2F(kh[0][3].y) * c2.y;
      acc.y = k0.y * c1.y
            + H2F(kh[1][0].x) * c1.x + H2F(kh[1][0].y) * c1.z
            + H2F(kh[1][1].x) * c0.y + H2F(kh[1][1].y) * c0.x
            + H2F(kh[1][2].x) * c0.z + H2F(kh[1][2].y) * c2.y
            + H2F(kh[1][3].x) * c2.x + H2F(kh[1][3].y) * c2.z;
      acc.z = k0.z * c1.z
            + H2F(kh[2][0].x) * c1.y + H2F(kh[2][0].y) * c1.w
            + H2F(kh[2][1].x) * c0.z + H2F(kh[2][1].y) * c0.y
            + H2F(kh[2][2].x) * c0.w + H2F(kh[2][2].y) * c2.z
            + H2F(kh[2][3].x) * c2.y + H2F(kh[2][3].y) * c2.w;
      acc.w = k0.w * c1.w
            + H2F(kh[3][0].x) * c1.z + H2F(kh[3][0].y) * r1
            + H2F(kh[3][1].x) * c0.w + H2F(kh[3][1].y) * c0.z
            + H2F(kh[3][2].x) * r0   + H2F(kh[3][2].y) * c2.w
            + H2F(kh[3][3].x) * c2.z + H2F(kh[3][3].y) * r2;
      *reinterpret_cast<float4*>(Xn + base) = acc;
      c1 = acc;
    }
    __syncthreads();
  }

  // ---- write 32x32 tile (step-6 result is in buf0; T even) ----
  float* yb = xout + (size_t)b * HW;
  int i  = tid >> 4;               // 0..31
  int pj = (tid & 15) * 2;         // 0..30
  float2 v = *reinterpret_cast<const float2*>(sX + (i + T) * XR + (pj + T));
  *reinterpret_cast<float2*>(yb + (size_t)(ti0 + i) * W + (tj0 + pj)) = v;
}

extern "C" void kernel_launch(void* const* d_in, const int* in_sizes, int n_in,
                              void* d_out, int out_size, void* d_ws,
                              size_t ws_size, hipStream_t stream) {
  const float* x  = (const float*)d_in[0];
  const float* Wa = (const float*)d_in[1];
  const float* ba = (const float*)d_in[2];
  float* out = (float*)d_out;

  __half* Kh = (__half*)d_ws;                   // 8N halves = 33.5 MB
  float* xa = (float*)d_ws + 4 * (size_t)N;     // after 16N bytes
  cspn_gen_kernel<<<dim3(N / 256), dim3(256), 0, stream>>>(x, Wa, ba, Kh);

  const float* src = x;
  for (int l = 0; l < 24 / T; ++l) {   // 4 launches of 6 fused steps
    float* dst = (l & 1) ? out : xa;   // l=3 (odd) -> final lands in d_out
    cspn_fused<<<dim3(NTILES), dim3(NT), 0, stream>>>(src, Kh, dst);
    src = dst;
  }
}